// Round 1
// baseline (2033.916 us; speedup 1.0000x reference)
//
#include <hip/hip_runtime.h>

#define NFEAT 5
#define HID 64

// ---------------- degree / norm ----------------
__global__ void k_deg_init(float* deg, int n) {
    int i = blockIdx.x * blockDim.x + threadIdx.x;
    if (i < n) deg[i] = 1.0f;  // self-loop contributes 1
}

__global__ void k_deg_edges(const int* __restrict__ dst, float* deg, int E) {
    int e = blockIdx.x * blockDim.x + threadIdx.x;
    if (e < E) unsafeAtomicAdd(&deg[dst[e]], 1.0f);
}

__global__ void k_rsqrt(float* deg, int n) {
    int i = blockIdx.x * blockDim.x + threadIdx.x;
    if (i < n) deg[i] = rsqrtf(deg[i]);   // deg >= 1 always
}

// ---------------- layer 1: aggregate 5-wide, then GEMM 5->64 + relu ----------------
__global__ void k_agg1_init(const float* __restrict__ x, const float* __restrict__ dis,
                            float* agg1, int n5) {
    int i = blockIdx.x * blockDim.x + threadIdx.x;
    if (i < n5) {
        int v = i / NFEAT;
        float dv = dis[v];
        agg1[i] = dv * dv * x[i];        // self-loop term, norm = dis[v]^2
    }
}

__global__ void k_agg1_edges(const int* __restrict__ src, const int* __restrict__ dst,
                             const float* __restrict__ x, const float* __restrict__ dis,
                             float* agg1, int E) {
    int e = blockIdx.x * blockDim.x + threadIdx.x;
    if (e >= E) return;
    int s = src[e], d = dst[e];
    float nrm = dis[s] * dis[d];
#pragma unroll
    for (int c = 0; c < NFEAT; ++c)
        unsafeAtomicAdd(&agg1[d * NFEAT + c], nrm * x[s * NFEAT + c]);
}

__global__ void k_gemm1(const float* __restrict__ agg1, const float* __restrict__ W1,
                        const float* __restrict__ b1, float* h1, int n64) {
    int i = blockIdx.x * blockDim.x + threadIdx.x;
    if (i >= n64) return;
    int v = i >> 6, c = i & 63;
    float acc = b1[c];
#pragma unroll
    for (int k = 0; k < NFEAT; ++k)
        acc += agg1[v * NFEAT + k] * W1[k * HID + c];
    h1[i] = fmaxf(acc, 0.0f);
}

// ---------------- layer 2: aggregate 64-wide, then GEMM 64->64 + relu ----------------
__global__ void k_agg2_init(const float* __restrict__ h1, const float* __restrict__ dis,
                            float* agg2, int n64) {
    int i = blockIdx.x * blockDim.x + threadIdx.x;
    if (i < n64) {
        float dv = dis[i >> 6];
        agg2[i] = dv * dv * h1[i];
    }
}

__global__ void k_agg2_edges(const int* __restrict__ src, const int* __restrict__ dst,
                             const float* __restrict__ h1, const float* __restrict__ dis,
                             float* agg2, int E) {
    int t = blockIdx.x * blockDim.x + threadIdx.x;
    int e = t >> 6;
    if (e >= E) return;
    int c = t & 63;                      // lane = channel
    int s = src[e], d = dst[e];          // broadcast loads within wave
    float nrm = dis[s] * dis[d];
    unsafeAtomicAdd(&agg2[(d << 6) + c], nrm * h1[(s << 6) + c]);
}

__global__ void k_gemm2(const float* __restrict__ agg2, const float* __restrict__ W2,
                        const float* __restrict__ b2, float* h2, int n64) {
    int i = blockIdx.x * blockDim.x + threadIdx.x;
    if (i >= n64) return;
    int v = i >> 6, c = i & 63;
    float acc = b2[c];
#pragma unroll
    for (int k = 0; k < HID; ++k)
        acc += agg2[(v << 6) + k] * W2[(k << 6) + c];   // row value broadcast, W2 coalesced/cached
    h2[i] = fmaxf(acc, 0.0f);
}

// ---------------- layer 3: project 64->1, then scalar aggregate ----------------
__global__ void k_dot3(const float* __restrict__ h2, const float* __restrict__ W3,
                       float* sv, int n) {
    int t = blockIdx.x * blockDim.x + threadIdx.x;
    int v = t >> 6, c = t & 63;
    if (v >= n) return;
    float val = h2[(v << 6) + c] * W3[c];
#pragma unroll
    for (int off = 32; off > 0; off >>= 1)
        val += __shfl_down(val, off, 64);
    if (c == 0) sv[v] = val;
}

__global__ void k_out_init(const float* __restrict__ sv, const float* __restrict__ dis,
                           const float* __restrict__ b3, float* out, int n) {
    int v = blockIdx.x * blockDim.x + threadIdx.x;
    if (v < n) {
        float dv = dis[v];
        out[v] = dv * dv * sv[v] + b3[0];
    }
}

__global__ void k_out_edges(const int* __restrict__ src, const int* __restrict__ dst,
                            const float* __restrict__ sv, const float* __restrict__ dis,
                            float* out, int E) {
    int e = blockIdx.x * blockDim.x + threadIdx.x;
    if (e >= E) return;
    int s = src[e], d = dst[e];
    unsafeAtomicAdd(&out[d], dis[s] * dis[d] * sv[s]);
}

extern "C" void kernel_launch(void* const* d_in, const int* in_sizes, int n_in,
                              void* d_out, int out_size, void* d_ws, size_t ws_size,
                              hipStream_t stream) {
    const float* x  = (const float*)d_in[0];
    const int*   ei = (const int*)d_in[1];
    const float* W1 = (const float*)d_in[2];
    const float* b1 = (const float*)d_in[3];
    const float* W2 = (const float*)d_in[4];
    const float* b2 = (const float*)d_in[5];
    const float* W3 = (const float*)d_in[6];
    const float* b3 = (const float*)d_in[7];
    float* out = (float*)d_out;

    const int n  = out_size;          // 100000 nodes
    const int E  = in_sizes[1] / 2;   // 3.2M edges
    const int* src = ei;
    const int* dst = ei + E;

    // workspace layout (float elements):
    // [0, n)                  dis (deg -> rsqrt in place)
    // [131072, +n*5)          agg1, later reused as sv (n scalars)
    // [655360, +n*64)         bufA: h1, later overwritten by h2
    // [655360+n*64, +n*64)    bufB: agg2
    float* ws   = (float*)d_ws;
    float* dis  = ws;
    float* agg1 = ws + 131072;
    float* bufA = ws + 131072 + 524288;
    float* bufB = bufA + (size_t)n * HID;
    float* sv   = agg1;               // reuse after gemm1

    const int B = 256;
    const int n5  = n * NFEAT;
    const int n64 = n * HID;

    k_deg_init  <<<(n + B - 1) / B, B, 0, stream>>>(dis, n);
    k_deg_edges <<<(E + B - 1) / B, B, 0, stream>>>(dst, dis, E);
    k_rsqrt     <<<(n + B - 1) / B, B, 0, stream>>>(dis, n);

    k_agg1_init <<<(n5 + B - 1) / B, B, 0, stream>>>(x, dis, agg1, n5);
    k_agg1_edges<<<(E + B - 1) / B, B, 0, stream>>>(src, dst, x, dis, agg1, E);
    k_gemm1     <<<(n64 + B - 1) / B, B, 0, stream>>>(agg1, W1, b1, bufA, n64);

    k_agg2_init <<<(n64 + B - 1) / B, B, 0, stream>>>(bufA, dis, bufB, n64);
    {
        long long tot = (long long)E * HID;
        int grid = (int)((tot + B - 1) / B);
        k_agg2_edges<<<grid, B, 0, stream>>>(src, dst, bufA, dis, bufB, E);
    }
    k_gemm2     <<<(n64 + B - 1) / B, B, 0, stream>>>(bufB, W2, b2, bufA, n64);

    k_dot3      <<<(n64 + B - 1) / B, B, 0, stream>>>(bufA, W3, sv, n);
    k_out_init  <<<(n + B - 1) / B, B, 0, stream>>>(sv, dis, b3, out, n);
    k_out_edges <<<(E + B - 1) / B, B, 0, stream>>>(src, dst, sv, dis, out, E);
}

// Round 2
// 989.600 us; speedup vs baseline: 2.0553x; 2.0553x over previous
//
#include <hip/hip_runtime.h>

#define NFEAT 5
#define HID 64

// ---------------- CSR build ----------------
__global__ void k_zero(int* p, int n) {
    int i = blockIdx.x * blockDim.x + threadIdx.x;
    if (i < n) p[i] = 0;
}

__global__ void k_hist(const int* __restrict__ dst, int* cnt, int E) {
    int e = blockIdx.x * blockDim.x + threadIdx.x;
    if (e < E) atomicAdd(&cnt[dst[e]], 1);
}

__global__ void k_dis(const int* __restrict__ cnt, float* dis, int n) {
    int i = blockIdx.x * blockDim.x + threadIdx.x;
    if (i < n) dis[i] = rsqrtf((float)cnt[i] + 1.0f);   // +1 self-loop
}

// single-block exclusive scan of cnt[0..n) -> row_ptr[0..n]
__global__ void k_scan(const int* __restrict__ cnt, int* row_ptr, int n) {
    __shared__ int sh[1024];
    __shared__ int carry_s;
    int t = threadIdx.x;
    if (t == 0) carry_s = 0;
    __syncthreads();
    for (int base = 0; base < n; base += 1024) {
        int v = (base + t < n) ? cnt[base + t] : 0;
        sh[t] = v;
        __syncthreads();
        for (int off = 1; off < 1024; off <<= 1) {
            int add = (t >= off) ? sh[t - off] : 0;
            __syncthreads();
            sh[t] += add;
            __syncthreads();
        }
        int incl = sh[t];
        int carry = carry_s;
        if (base + t < n) row_ptr[base + t] = carry + incl - v;  // exclusive
        __syncthreads();
        if (t == 1023) carry_s = carry + incl;                   // chunk total
        __syncthreads();
    }
    if (t == 0) row_ptr[n] = carry_s;
}

__global__ void k_fill(const int* __restrict__ src, const int* __restrict__ dst,
                       const int* __restrict__ row_ptr, int* cursor,
                       int* csr, int E) {
    int e = blockIdx.x * blockDim.x + threadIdx.x;
    if (e >= E) return;
    int d = dst[e];
    int pos = row_ptr[d] + atomicAdd(&cursor[d], 1);
    csr[pos] = src[e];
}

// ---------------- layer 1 fused: gather 5-wide + GEMM 5->64 + relu ----------------
__global__ void k_layer1(const int* __restrict__ rp, const int* __restrict__ csr,
                         const float* __restrict__ x, const float* __restrict__ dis,
                         const float* __restrict__ W1, const float* __restrict__ b1,
                         float* __restrict__ h1, int n) {
    int wave = (blockIdx.x * blockDim.x + threadIdx.x) >> 6;
    int lane = threadIdx.x & 63;
    if (wave >= n) return;
    int v = wave;
    int r0 = rp[v], r1 = rp[v + 1];
    float a0 = 0.f, a1 = 0.f, a2 = 0.f, a3 = 0.f, a4 = 0.f;
    for (int j = r0 + lane; j < r1; j += 64) {
        int s = csr[j];
        float w = dis[s];
        const float* xs = x + s * NFEAT;
        a0 += w * xs[0]; a1 += w * xs[1]; a2 += w * xs[2];
        a3 += w * xs[3]; a4 += w * xs[4];
    }
#pragma unroll
    for (int m = 32; m > 0; m >>= 1) {
        a0 += __shfl_xor(a0, m, 64); a1 += __shfl_xor(a1, m, 64);
        a2 += __shfl_xor(a2, m, 64); a3 += __shfl_xor(a3, m, 64);
        a4 += __shfl_xor(a4, m, 64);
    }
    float dv = dis[v];
    const float* xv = x + v * NFEAT;
    a0 = dv * (a0 + dv * xv[0]);
    a1 = dv * (a1 + dv * xv[1]);
    a2 = dv * (a2 + dv * xv[2]);
    a3 = dv * (a3 + dv * xv[3]);
    a4 = dv * (a4 + dv * xv[4]);
    int c = lane;
    float h = b1[c] + a0 * W1[c] + a1 * W1[64 + c] + a2 * W1[128 + c]
            + a3 * W1[192 + c] + a4 * W1[256 + c];
    h1[(size_t)v * HID + c] = fmaxf(h, 0.0f);
}

// ------- layer 2+3 fused: gather 64-wide + GEMM 64x64 + relu + dot W3 -> sv -------
__global__ __launch_bounds__(256) void
k_layer23(const int* __restrict__ rp, const int* __restrict__ csr,
          const float* __restrict__ h1, const float* __restrict__ dis,
          const float* __restrict__ W2, const float* __restrict__ b2,
          const float* __restrict__ W3, float* __restrict__ sv, int n) {
    __shared__ float W2s[HID * HID];
    for (int i = threadIdx.x; i < HID * HID; i += 256) W2s[i] = W2[i];
    __syncthreads();
    int wave = (blockIdx.x * blockDim.x + threadIdx.x) >> 6;
    int lane = threadIdx.x & 63;
    if (wave >= n) return;
    int v = wave;
    int r0 = rp[v], r1 = rp[v + 1];
    float dv = dis[v];
    float acc = dv * h1[(size_t)v * HID + lane];       // self-loop (scaled by dv below)
    for (int j = r0; j < r1; ++j) {
        int s = csr[j];                                 // wave-broadcast load
        float w = dis[s];
        acc += w * h1[(size_t)s * HID + lane];          // 256B lane-contiguous gather
    }
    acc *= dv;                                          // agg2[v, lane]
    // h2[v,c] = relu(b2[c] + sum_k agg[k] * W2[k,c]) ; agg[k] lives in lane k
    float out = b2[lane];
#pragma unroll
    for (int k = 0; k < HID; ++k)
        out += __shfl(acc, k, 64) * W2s[(k << 6) + lane];
    out = fmaxf(out, 0.0f);
    // sv[v] = sum_c h2[v,c] * W3[c]
    float val = out * W3[lane];
#pragma unroll
    for (int m = 32; m > 0; m >>= 1) val += __shfl_xor(val, m, 64);
    if (lane == 0) sv[v] = val;
}

// ---------------- output: gather scalars ----------------
__global__ void k_out(const int* __restrict__ rp, const int* __restrict__ csr,
                      const float* __restrict__ sv, const float* __restrict__ dis,
                      const float* __restrict__ b3, float* __restrict__ out, int n) {
    int wave = (blockIdx.x * blockDim.x + threadIdx.x) >> 6;
    int lane = threadIdx.x & 63;
    if (wave >= n) return;
    int v = wave;
    int r0 = rp[v], r1 = rp[v + 1];
    float acc = 0.f;
    for (int j = r0 + lane; j < r1; j += 64) {
        int s = csr[j];
        acc += dis[s] * sv[s];
    }
#pragma unroll
    for (int m = 32; m > 0; m >>= 1) acc += __shfl_xor(acc, m, 64);
    if (lane == 0) {
        float dv = dis[v];
        out[v] = b3[0] + dv * (acc + dv * sv[v]);
    }
}

extern "C" void kernel_launch(void* const* d_in, const int* in_sizes, int n_in,
                              void* d_out, int out_size, void* d_ws, size_t ws_size,
                              hipStream_t stream) {
    const float* x  = (const float*)d_in[0];
    const int*   ei = (const int*)d_in[1];
    const float* W1 = (const float*)d_in[2];
    const float* b1 = (const float*)d_in[3];
    const float* W2 = (const float*)d_in[4];
    const float* b2 = (const float*)d_in[5];
    const float* W3 = (const float*)d_in[6];
    const float* b3 = (const float*)d_in[7];
    float* out = (float*)d_out;

    const int n = out_size;           // 100000
    const int E = in_sizes[1] / 2;    // 3200000
    const int* src = ei;
    const int* dst = ei + E;

    // workspace layout (4B elements): cnt[n] cursor[n] row_ptr[n+1] dis[n] sv[n] csr[E] h1[n*64]
    int*   cnt = (int*)d_ws;
    int*   cur = cnt + n;
    int*   rp  = cur + n;
    float* dis = (float*)(rp + n + 1);
    float* sv  = dis + n;
    int*   csr = (int*)(sv + n);
    float* h1  = (float*)(csr + E);

    const int B = 256;
    const int gridE = (E + B - 1) / B;
    const int gridN = (n + B - 1) / B;
    const int gridW = (n * 64 + B - 1) / B;   // one wave per node

    k_zero   <<<(2 * n + B - 1) / B, B, 0, stream>>>(cnt, 2 * n);  // cnt + cursor
    k_hist   <<<gridE, B, 0, stream>>>(dst, cnt, E);
    k_dis    <<<gridN, B, 0, stream>>>(cnt, dis, n);
    k_scan   <<<1, 1024, 0, stream>>>(cnt, rp, n);
    k_fill   <<<gridE, B, 0, stream>>>(src, dst, rp, cur, csr, E);

    k_layer1 <<<gridW, B, 0, stream>>>(rp, csr, x, dis, W1, b1, h1, n);
    k_layer23<<<gridW, B, 0, stream>>>(rp, csr, h1, dis, W2, b2, W3, sv, n);
    k_out    <<<gridW, B, 0, stream>>>(rp, csr, sv, dis, b3, out, n);
}

// Round 3
// 654.157 us; speedup vs baseline: 3.1092x; 1.5128x over previous
//
#include <hip/hip_runtime.h>

#define NFEAT 5
#define HID 64

// ---------------- CSR build ----------------
__global__ void k_zero(int* p, int n) {
    int i = blockIdx.x * blockDim.x + threadIdx.x;
    if (i < n) p[i] = 0;
}

__global__ void k_hist(const int* __restrict__ dst, int* cnt, int E) {
    int e = blockIdx.x * blockDim.x + threadIdx.x;
    if (e < E) atomicAdd(&cnt[dst[e]], 1);
}

// dis[i] = rsqrt(deg) ; xs[i,:] = dis[i] * x[i,:]
__global__ void k_dis_xscale(const int* __restrict__ cnt, const float* __restrict__ x,
                             float* dis, float* xs, int n) {
    int i = blockIdx.x * blockDim.x + threadIdx.x;
    if (i >= n) return;
    float d = rsqrtf((float)cnt[i] + 1.0f);   // +1 self-loop
    dis[i] = d;
#pragma unroll
    for (int c = 0; c < NFEAT; ++c) xs[i * NFEAT + c] = d * x[i * NFEAT + c];
}

// ---- 3-phase exclusive scan of cnt[0..n) -> rp[0..n] ----
__global__ void k_scan_partial(const int* __restrict__ cnt, int* part, int n) {
    __shared__ int sh[256];
    int t = threadIdx.x, gid = blockIdx.x * 256 + t;
    sh[t] = (gid < n) ? cnt[gid] : 0;
    __syncthreads();
    for (int off = 128; off > 0; off >>= 1) {
        if (t < off) sh[t] += sh[t + off];
        __syncthreads();
    }
    if (t == 0) part[blockIdx.x] = sh[0];
}

__global__ void k_scan_part(int* part, int nb) {   // single block, exclusive in place
    __shared__ int sh[1024];
    int t = threadIdx.x;
    int v = (t < nb) ? part[t] : 0;
    sh[t] = v;
    __syncthreads();
    for (int off = 1; off < 1024; off <<= 1) {
        int a = (t >= off) ? sh[t - off] : 0;
        __syncthreads();
        sh[t] += a;
        __syncthreads();
    }
    if (t < nb) part[t] = sh[t] - v;
}

__global__ void k_scan_final(const int* __restrict__ cnt, const int* __restrict__ part,
                             int* rp, int n) {
    __shared__ int sh[256];
    int t = threadIdx.x, gid = blockIdx.x * 256 + t;
    int v = (gid < n) ? cnt[gid] : 0;
    sh[t] = v;
    __syncthreads();
    for (int off = 1; off < 256; off <<= 1) {
        int a = (t >= off) ? sh[t - off] : 0;
        __syncthreads();
        sh[t] += a;
        __syncthreads();
    }
    if (gid < n)     rp[gid] = part[blockIdx.x] + sh[t] - v;
    if (gid == n - 1) rp[n]  = part[blockIdx.x] + sh[t];
}

__global__ void k_fill(const int* __restrict__ src, const int* __restrict__ dst,
                       const int* __restrict__ rp, int* cursor, int* csr, int E) {
    int e = blockIdx.x * blockDim.x + threadIdx.x;
    if (e >= E) return;
    int d = dst[e];
    int pos = rp[d] + atomicAdd(&cursor[d], 1);
    csr[pos] = src[e];
}

// ---------------- layer 1 fused: gather xs (5-wide) + GEMM 5->64 + relu, write g1=dis*h1 ----
__global__ void k_layer1(const int* __restrict__ rp, const int* __restrict__ csr,
                         const float* __restrict__ xs, const float* __restrict__ dis,
                         const float* __restrict__ W1, const float* __restrict__ b1,
                         float* __restrict__ g1, int n) {
    int wave = (blockIdx.x * blockDim.x + threadIdx.x) >> 6;
    int lane = threadIdx.x & 63;
    if (wave >= n) return;
    int v = wave;
    int r0 = rp[v], r1 = rp[v + 1];
    float a0 = 0.f, a1 = 0.f, a2 = 0.f, a3 = 0.f, a4 = 0.f;
    for (int j = r0 + lane; j < r1; j += 64) {
        const float* p = xs + (size_t)csr[j] * NFEAT;
        a0 += p[0]; a1 += p[1]; a2 += p[2]; a3 += p[3]; a4 += p[4];
    }
#pragma unroll
    for (int m = 32; m > 0; m >>= 1) {
        a0 += __shfl_xor(a0, m, 64); a1 += __shfl_xor(a1, m, 64);
        a2 += __shfl_xor(a2, m, 64); a3 += __shfl_xor(a3, m, 64);
        a4 += __shfl_xor(a4, m, 64);
    }
    float dv = dis[v];
    const float* pv = xs + (size_t)v * NFEAT;
    a0 = dv * (a0 + pv[0]); a1 = dv * (a1 + pv[1]); a2 = dv * (a2 + pv[2]);
    a3 = dv * (a3 + pv[3]); a4 = dv * (a4 + pv[4]);
    int c = lane;
    float h = b1[c] + a0 * W1[c] + a1 * W1[64 + c] + a2 * W1[128 + c]
            + a3 * W1[192 + c] + a4 * W1[256 + c];
    g1[(size_t)v * HID + c] = dv * fmaxf(h, 0.0f);     // pre-scaled for layer-2 gather
}

// ------- layer 2+3 fused: gather g1 (64-wide, unroll 8) + GEMM 64x64 + relu + dot W3 ->
//         svs[v] = dis[v] * (W3 . h2[v])
__global__ __launch_bounds__(256) void
k_layer23(const int* __restrict__ rp, const int* __restrict__ csr,
          const float* __restrict__ g1, const float* __restrict__ dis,
          const float* __restrict__ W2, const float* __restrict__ b2,
          const float* __restrict__ W3, float* __restrict__ svs, int n) {
    __shared__ float W2s[HID * HID];
    for (int i = threadIdx.x; i < HID * HID; i += 256) W2s[i] = W2[i];
    __syncthreads();
    int wave = (blockIdx.x * blockDim.x + threadIdx.x) >> 6;
    int lane = threadIdx.x & 63;
    if (wave >= n) return;
    int v = wave;
    int r0 = rp[v], r1 = rp[v + 1];
    float acc = g1[(size_t)v * HID + lane];            // self term (= dv*h1[v])
    int j = r0;
    for (; j + 8 <= r1; j += 8) {
        int s0 = csr[j],     s1 = csr[j + 1], s2 = csr[j + 2], s3 = csr[j + 3];
        int s4 = csr[j + 4], s5 = csr[j + 5], s6 = csr[j + 6], s7 = csr[j + 7];
        float t0 = g1[(size_t)s0 * HID + lane];
        float t1 = g1[(size_t)s1 * HID + lane];
        float t2 = g1[(size_t)s2 * HID + lane];
        float t3 = g1[(size_t)s3 * HID + lane];
        float t4 = g1[(size_t)s4 * HID + lane];
        float t5 = g1[(size_t)s5 * HID + lane];
        float t6 = g1[(size_t)s6 * HID + lane];
        float t7 = g1[(size_t)s7 * HID + lane];
        acc += ((t0 + t1) + (t2 + t3)) + ((t4 + t5) + (t6 + t7));
    }
    for (; j < r1; ++j) acc += g1[(size_t)csr[j] * HID + lane];
    acc *= dis[v];                                     // agg2[v, lane]
    // h2[v,c] = relu(b2[c] + sum_k agg[k] * W2[k,c]) ; agg[k] lives in lane k
    float out = b2[lane];
#pragma unroll
    for (int k = 0; k < HID; ++k)
        out += __shfl(acc, k, 64) * W2s[(k << 6) + lane];
    out = fmaxf(out, 0.0f);
    float val = out * W3[lane];
#pragma unroll
    for (int m = 32; m > 0; m >>= 1) val += __shfl_xor(val, m, 64);
    if (lane == 0) svs[v] = dis[v] * val;              // pre-scaled for output gather
}

// ---------------- output: gather scalars ----------------
__global__ void k_out(const int* __restrict__ rp, const int* __restrict__ csr,
                      const float* __restrict__ svs, const float* __restrict__ dis,
                      const float* __restrict__ b3, float* __restrict__ out, int n) {
    int wave = (blockIdx.x * blockDim.x + threadIdx.x) >> 6;
    int lane = threadIdx.x & 63;
    if (wave >= n) return;
    int v = wave;
    int r0 = rp[v], r1 = rp[v + 1];
    float acc = (lane == 0) ? svs[v] : 0.f;            // self term
    for (int j = r0 + lane; j < r1; j += 64) acc += svs[csr[j]];
#pragma unroll
    for (int m = 32; m > 0; m >>= 1) acc += __shfl_xor(acc, m, 64);
    if (lane == 0) out[v] = b3[0] + dis[v] * acc;
}

extern "C" void kernel_launch(void* const* d_in, const int* in_sizes, int n_in,
                              void* d_out, int out_size, void* d_ws, size_t ws_size,
                              hipStream_t stream) {
    const float* x  = (const float*)d_in[0];
    const int*   ei = (const int*)d_in[1];
    const float* W1 = (const float*)d_in[2];
    const float* b1 = (const float*)d_in[3];
    const float* W2 = (const float*)d_in[4];
    const float* b2 = (const float*)d_in[5];
    const float* W3 = (const float*)d_in[6];
    const float* b3 = (const float*)d_in[7];
    float* out = (float*)d_out;

    const int n = out_size;           // 100000
    const int E = in_sizes[1] / 2;    // 3200000
    const int* src = ei;
    const int* dst = ei + E;

    // ws layout (4B): cnt[n] cur[n] rp[n+1] dis[n] svs[n] part[1024] csr[E] xs[5n] g1[64n]
    int*   cnt  = (int*)d_ws;
    int*   cur  = cnt + n;
    int*   rp   = cur + n;
    float* dis  = (float*)(rp + n + 1);
    float* svs  = dis + n;
    int*   part = (int*)(svs + n);
    int*   csr  = part + 1024;
    float* xs   = (float*)(csr + E);
    float* g1   = xs + (size_t)n * NFEAT;

    const int B = 256;
    const int gridE = (E + B - 1) / B;
    const int gridN = (n + B - 1) / B;
    const int gridW = (n * 64 + B - 1) / B;   // one wave per node
    const int nb    = (n + 255) / 256;        // scan blocks (391)

    k_zero        <<<(2 * n + B - 1) / B, B, 0, stream>>>(cnt, 2 * n);  // cnt + cursor
    k_hist        <<<gridE, B, 0, stream>>>(dst, cnt, E);
    k_dis_xscale  <<<gridN, B, 0, stream>>>(cnt, x, dis, xs, n);
    k_scan_partial<<<nb, 256, 0, stream>>>(cnt, part, n);
    k_scan_part   <<<1, 1024, 0, stream>>>(part, nb);
    k_scan_final  <<<nb, 256, 0, stream>>>(cnt, part, rp, n);
    k_fill        <<<gridE, B, 0, stream>>>(src, dst, rp, cur, csr, E);

    k_layer1      <<<gridW, B, 0, stream>>>(rp, csr, xs, dis, W1, b1, g1, n);
    k_layer23     <<<gridW, B, 0, stream>>>(rp, csr, g1, dis, W2, b2, W3, svs, n);
    k_out         <<<gridW, B, 0, stream>>>(rp, csr, svs, dis, b3, out, n);
}

// Round 4
// 597.551 us; speedup vs baseline: 3.4038x; 1.0947x over previous
//
#include <hip/hip_runtime.h>
#include <hip/hip_fp16.h>

#define NFEAT 5
#define HID 64
#define BSH 11              // bucket = dst >> 11 (2048 nodes/bucket)
#define NBK 64              // allocated buckets (49 used for n=100000)
#define CHUNK 2048          // edges per bin block

// ---------------- CSR build ----------------
__global__ void k_zero(int* p, int n) {
    int i = blockIdx.x * blockDim.x + threadIdx.x;
    if (i < n) p[i] = 0;
}

__global__ void k_hist(const int* __restrict__ dst, int* cnt, int E) {
    int e = blockIdx.x * blockDim.x + threadIdx.x;
    if (e < E) atomicAdd(&cnt[dst[e]], 1);
}

// dis[i] = rsqrt(deg) ; xs[i,:] = dis[i] * x[i,:]
__global__ void k_dis_xscale(const int* __restrict__ cnt, const float* __restrict__ x,
                             float* dis, float* xs, int n) {
    int i = blockIdx.x * blockDim.x + threadIdx.x;
    if (i >= n) return;
    float d = rsqrtf((float)cnt[i] + 1.0f);   // +1 self-loop
    dis[i] = d;
#pragma unroll
    for (int c = 0; c < NFEAT; ++c) xs[i * NFEAT + c] = d * x[i * NFEAT + c];
}

// ---- 3-phase exclusive scan of cnt[0..n) -> rp[0..n] ----
__global__ void k_scan_partial(const int* __restrict__ cnt, int* part, int n) {
    __shared__ int sh[256];
    int t = threadIdx.x, gid = blockIdx.x * 256 + t;
    sh[t] = (gid < n) ? cnt[gid] : 0;
    __syncthreads();
    for (int off = 128; off > 0; off >>= 1) {
        if (t < off) sh[t] += sh[t + off];
        __syncthreads();
    }
    if (t == 0) part[blockIdx.x] = sh[0];
}

__global__ void k_scan_part(int* part, int nb) {   // single block, exclusive in place
    __shared__ int sh[1024];
    int t = threadIdx.x;
    int v = (t < nb) ? part[t] : 0;
    sh[t] = v;
    __syncthreads();
    for (int off = 1; off < 1024; off <<= 1) {
        int a = (t >= off) ? sh[t - off] : 0;
        __syncthreads();
        sh[t] += a;
        __syncthreads();
    }
    if (t < nb) part[t] = sh[t] - v;
}

__global__ void k_scan_final(const int* __restrict__ cnt, const int* __restrict__ part,
                             int* rp, int n) {
    __shared__ int sh[256];
    int t = threadIdx.x, gid = blockIdx.x * 256 + t;
    int v = (gid < n) ? cnt[gid] : 0;
    sh[t] = v;
    __syncthreads();
    for (int off = 1; off < 256; off <<= 1) {
        int a = (t >= off) ? sh[t - off] : 0;
        __syncthreads();
        sh[t] += a;
        __syncthreads();
    }
    if (gid < n)      rp[gid] = part[blockIdx.x] + sh[t] - v;
    if (gid == n - 1) rp[n]   = part[blockIdx.x] + sh[t];
}

__global__ void k_bcur(const int* __restrict__ rp, int* bcur, int n) {
    int t = threadIdx.x;   // 64 threads
    int idx = t << BSH;
    if (idx > n) idx = n;
    bcur[t] = rp[idx];
}

// bin edges by dst>>BSH with LDS multi-split; output runs are bucket-contiguous
__global__ __launch_bounds__(256) void
k_bin(const int* __restrict__ src, const int* __restrict__ dst,
      int* bcur, int2* __restrict__ binned, int E) {
    __shared__ int2 stg[CHUNK];
    __shared__ int hist[NBK], base[NBK], gb[NBK];
    int t = threadIdx.x;
    int e0 = blockIdx.x * CHUNK;
    int cc = E - e0; if (cc > CHUNK) cc = CHUNK;
    if (t < NBK) hist[t] = 0;
    __syncthreads();
    int2 my[CHUNK / 256]; int mb[CHUNK / 256];
#pragma unroll
    for (int k = 0; k < CHUNK / 256; ++k) {
        int i = e0 + k * 256 + t;
        if (i < E) {
            my[k].x = src[i]; my[k].y = dst[i];
            mb[k] = my[k].y >> BSH;
            atomicAdd(&hist[mb[k]], 1);
        } else mb[k] = -1;
    }
    __syncthreads();
    if (t < NBK) {     // threads 0..63 == wave 0: exclusive scan + global reserve
        int c = hist[t];
        int x = c;
#pragma unroll
        for (int off = 1; off < 64; off <<= 1) {
            int y = __shfl_up(x, off, 64);
            if (t >= off) x += y;
        }
        base[t] = x - c;
        gb[t] = (c > 0) ? atomicAdd(&bcur[t], c) : 0;
        hist[t] = 0;   // reuse as placement cursor
    }
    __syncthreads();
#pragma unroll
    for (int k = 0; k < CHUNK / 256; ++k) {
        if (mb[k] >= 0) {
            int p = base[mb[k]] + atomicAdd(&hist[mb[k]], 1);
            stg[p] = my[k];
        }
    }
    __syncthreads();
#pragma unroll
    for (int k = 0; k < CHUNK / 256; ++k) {
        int p = k * 256 + t;
        if (p < cc) {
            int2 v = stg[p];
            int b = v.y >> BSH;
            binned[gb[b] + (p - base[b])] = v;
        }
    }
}

// local fill: binned edges are bucket-grouped -> csr writes stay in L2-resident windows
__global__ void k_fill2(const int2* __restrict__ binned, const int* __restrict__ rp,
                        int* cursor, int* __restrict__ csr, int E) {
    int i = blockIdx.x * blockDim.x + threadIdx.x;
    if (i >= E) return;
    int2 v = binned[i];
    int pos = rp[v.y] + atomicAdd(&cursor[v.y], 1);
    csr[pos] = v.x;
}

// ---------------- layer 1 fused: gather xs (5-wide) + GEMM 5->64 + relu, g1h=fp16(dis*h1) ----
__global__ void k_layer1(const int* __restrict__ rp, const int* __restrict__ csr,
                         const float* __restrict__ xs, const float* __restrict__ dis,
                         const float* __restrict__ W1, const float* __restrict__ b1,
                         __half* __restrict__ g1h, int n) {
    int wave = (blockIdx.x * blockDim.x + threadIdx.x) >> 6;
    int lane = threadIdx.x & 63;
    if (wave >= n) return;
    int v = wave;
    int r0 = rp[v], r1 = rp[v + 1];
    float a0 = 0.f, a1 = 0.f, a2 = 0.f, a3 = 0.f, a4 = 0.f;
    for (int j = r0 + lane; j < r1; j += 64) {
        const float* p = xs + (size_t)csr[j] * NFEAT;
        a0 += p[0]; a1 += p[1]; a2 += p[2]; a3 += p[3]; a4 += p[4];
    }
#pragma unroll
    for (int m = 32; m > 0; m >>= 1) {
        a0 += __shfl_xor(a0, m, 64); a1 += __shfl_xor(a1, m, 64);
        a2 += __shfl_xor(a2, m, 64); a3 += __shfl_xor(a3, m, 64);
        a4 += __shfl_xor(a4, m, 64);
    }
    float dv = dis[v];
    const float* pv = xs + (size_t)v * NFEAT;
    a0 = dv * (a0 + pv[0]); a1 = dv * (a1 + pv[1]); a2 = dv * (a2 + pv[2]);
    a3 = dv * (a3 + pv[3]); a4 = dv * (a4 + pv[4]);
    int c = lane;
    float h = b1[c] + a0 * W1[c] + a1 * W1[64 + c] + a2 * W1[128 + c]
            + a3 * W1[192 + c] + a4 * W1[256 + c];
    g1h[(size_t)v * HID + c] = __float2half(dv * fmaxf(h, 0.0f));
}

// ------- layer 2+3 fused: gather g1h (fp16, unroll 8) + GEMM 64x64 + relu + dot W3 ----
__global__ __launch_bounds__(256) void
k_layer23(const int* __restrict__ rp, const int* __restrict__ csr,
          const __half* __restrict__ g1h, const float* __restrict__ dis,
          const float* __restrict__ W2, const float* __restrict__ b2,
          const float* __restrict__ W3, float* __restrict__ svs, int n) {
    __shared__ float W2s[HID * HID];
    for (int i = threadIdx.x; i < HID * HID; i += 256) W2s[i] = W2[i];
    __syncthreads();
    int wave = (blockIdx.x * blockDim.x + threadIdx.x) >> 6;
    int lane = threadIdx.x & 63;
    if (wave >= n) return;
    int v = wave;
    int r0 = rp[v], r1 = rp[v + 1];
    float acc = __half2float(g1h[(size_t)v * HID + lane]);   // self term
    int j = r0;
    for (; j + 8 <= r1; j += 8) {
        int s0 = csr[j],     s1 = csr[j + 1], s2 = csr[j + 2], s3 = csr[j + 3];
        int s4 = csr[j + 4], s5 = csr[j + 5], s6 = csr[j + 6], s7 = csr[j + 7];
        float t0 = __half2float(g1h[(size_t)s0 * HID + lane]);
        float t1 = __half2float(g1h[(size_t)s1 * HID + lane]);
        float t2 = __half2float(g1h[(size_t)s2 * HID + lane]);
        float t3 = __half2float(g1h[(size_t)s3 * HID + lane]);
        float t4 = __half2float(g1h[(size_t)s4 * HID + lane]);
        float t5 = __half2float(g1h[(size_t)s5 * HID + lane]);
        float t6 = __half2float(g1h[(size_t)s6 * HID + lane]);
        float t7 = __half2float(g1h[(size_t)s7 * HID + lane]);
        acc += ((t0 + t1) + (t2 + t3)) + ((t4 + t5) + (t6 + t7));
    }
    for (; j < r1; ++j) acc += __half2float(g1h[(size_t)csr[j] * HID + lane]);
    acc *= dis[v];                                     // agg2[v, lane]
    float out = b2[lane];
#pragma unroll
    for (int k = 0; k < HID; ++k)
        out += __shfl(acc, k, 64) * W2s[(k << 6) + lane];
    out = fmaxf(out, 0.0f);
    float val = out * W3[lane];
#pragma unroll
    for (int m = 32; m > 0; m >>= 1) val += __shfl_xor(val, m, 64);
    if (lane == 0) svs[v] = dis[v] * val;              // pre-scaled for output gather
}

// ---------------- output: gather scalars ----------------
__global__ void k_out(const int* __restrict__ rp, const int* __restrict__ csr,
                      const float* __restrict__ svs, const float* __restrict__ dis,
                      const float* __restrict__ b3, float* __restrict__ out, int n) {
    int wave = (blockIdx.x * blockDim.x + threadIdx.x) >> 6;
    int lane = threadIdx.x & 63;
    if (wave >= n) return;
    int v = wave;
    int r0 = rp[v], r1 = rp[v + 1];
    float acc = (lane == 0) ? svs[v] : 0.f;            // self term
    for (int j = r0 + lane; j < r1; j += 64) acc += svs[csr[j]];
#pragma unroll
    for (int m = 32; m > 0; m >>= 1) acc += __shfl_xor(acc, m, 64);
    if (lane == 0) out[v] = b3[0] + dis[v] * acc;
}

extern "C" void kernel_launch(void* const* d_in, const int* in_sizes, int n_in,
                              void* d_out, int out_size, void* d_ws, size_t ws_size,
                              hipStream_t stream) {
    const float* x  = (const float*)d_in[0];
    const int*   ei = (const int*)d_in[1];
    const float* W1 = (const float*)d_in[2];
    const float* b1 = (const float*)d_in[3];
    const float* W2 = (const float*)d_in[4];
    const float* b2 = (const float*)d_in[5];
    const float* W3 = (const float*)d_in[6];
    const float* b3 = (const float*)d_in[7];
    float* out = (float*)d_out;

    const int n = out_size;           // 100000
    const int E = in_sizes[1] / 2;    // 3200000
    const int* src = ei;
    const int* dst = ei + E;

    // ws layout (4B units):
    // cnt[n] cur[n] rp[n+2] dis[n] svs[n] part[1024] bcur[64] csr[E] binned[2E] xs[5n]
    // g1h aliases binned (dead after k_fill2); 64n halves = 32n ints <= 2E ints.
    int*    cnt    = (int*)d_ws;
    int*    cur    = cnt + n;
    int*    rp     = cur + n;
    float*  dis    = (float*)(rp + n + 2);
    float*  svs    = dis + n;
    int*    part   = (int*)(svs + n);
    int*    bcur   = part + 1024;
    int*    csr    = bcur + 64;
    int2*   binned = (int2*)(csr + E);
    float*  xs     = (float*)(binned + E);
    __half* g1h    = (__half*)binned;

    const int B = 256;
    const int gridE = (E + B - 1) / B;
    const int gridN = (n + B - 1) / B;
    const int gridW = (n * 64 + B - 1) / B;   // one wave per node
    const int nb    = (n + 255) / 256;        // scan blocks (391)
    const int gridB = (E + CHUNK - 1) / CHUNK;

    k_zero        <<<(2 * n + B - 1) / B, B, 0, stream>>>(cnt, 2 * n);  // cnt + cursor
    k_hist        <<<gridE, B, 0, stream>>>(dst, cnt, E);
    k_dis_xscale  <<<gridN, B, 0, stream>>>(cnt, x, dis, xs, n);
    k_scan_partial<<<nb, 256, 0, stream>>>(cnt, part, n);
    k_scan_part   <<<1, 1024, 0, stream>>>(part, nb);
    k_scan_final  <<<nb, 256, 0, stream>>>(cnt, part, rp, n);
    k_bcur        <<<1, 64, 0, stream>>>(rp, bcur, n);
    k_bin         <<<gridB, 256, 0, stream>>>(src, dst, bcur, binned, E);
    k_fill2       <<<gridE, B, 0, stream>>>(binned, rp, cur, csr, E);

    k_layer1      <<<gridW, B, 0, stream>>>(rp, csr, xs, dis, W1, b1, g1h, n);
    k_layer23     <<<gridW, B, 0, stream>>>(rp, csr, g1h, dis, W2, b2, W3, svs, n);
    k_out         <<<gridW, B, 0, stream>>>(rp, csr, svs, dis, b3, out, n);
}